// Round 8
// baseline (296.014 us; speedup 1.0000x reference)
//
#include <hip/hip_runtime.h>

#define BATCH 8
#define NUM_GENES 20000
#define FEAT 64
#define TASK_CHUNK 2

// Pass 1: find segment start offsets from sorted segment_ids.
// Block 0 also zeroes the 8 per-XCD work-queue counters (stream-ordered
// before the pool kernel).
__global__ __launch_bounds__(256)
void find_starts_kernel(const int* __restrict__ segment_ids,
                        int* __restrict__ starts, int* __restrict__ workctr,
                        int total)
{
    if (blockIdx.x == 0 && threadIdx.x < BATCH) workctr[threadIdx.x] = 0;
    int i = blockIdx.x * 256 + threadIdx.x;
    if (i < total) {
        int s = segment_ids[i];
        if (i == 0 || segment_ids[i - 1] != s) starts[s] = i;
    }
}

// Pass 2: persistent waves + per-XCD work queue.
// Block's batch b = bid & 7 (XCD pinning: verified R2, FETCH 157->70 MB;
// batch plane 5.12 MB ~fits one XCD L2). Each wave grabs TASK_CHUNK
// segments for its batch via atomicAdd on workctr[b] until drained --
// fixes the ~9x segment-size spread that left block slots waiting on
// their slowest wave (R7 theory: occupancy 55-65%).
// Inner loop: depth-8 issue-then-drain sawtooth (verified R5: -25%),
// shfl-broadcast prescaled indices.
__global__ __launch_bounds__(256)
void genesets_pool_kernel(const float* __restrict__ gene,        // [B][G][F]
                          const int*   __restrict__ flat_indices,// [total]
                          const int*   __restrict__ starts,      // [S]
                          const int*   __restrict__ counts,      // [S]
                          float*       __restrict__ out,         // [B][S][F]
                          int num_segments, int* __restrict__ workctr)
{
    const int b    = blockIdx.x & 7;               // batch -> XCD
    const int lane = threadIdx.x & 63;
    const int sub  = lane >> 4;                    // 0..3
    const int fq   = lane & 15;                    // feature quad

    const float* gbase = gene + (size_t)b * NUM_GENES * FEAT + fq * 4;

    for (;;) {
        int t0;
        if (lane == 0) t0 = atomicAdd(&workctr[b], TASK_CHUNK);
        t0 = __shfl(t0, 0);
        if (t0 >= num_segments) break;
        const int tend = (t0 + TASK_CHUNK < num_segments) ? t0 + TASK_CHUNK
                                                          : num_segments;

        for (int s = t0; s < tend; ++s) {
            const int start = starts[s];
            const int cnt   = counts[s];

            // Stage all indices, pre-scaled to element offsets (cnt < 128).
            int off_a = (lane      < cnt) ? flat_indices[start + lane]      * FEAT : 0;
            int off_b = (lane + 64 < cnt) ? flat_indices[start + lane + 64] * FEAT : 0;

            float4 acc = make_float4(0.f, 0.f, 0.f, 0.f);
            const int kn = (cnt + 3) >> 2;         // quads, <= 23

            for (int c = 0; c < kn; c += 8) {
                float4 buf[8];
                #pragma unroll
                for (int p = 0; p < 8; ++p) {
                    const int k = c + p;
                    const int j = sub + 4 * k;
                    const int off = (j < 64) ? __shfl(off_a, j) : __shfl(off_b, j & 63);
                    if (k < kn && j < cnt) {
                        buf[p] = *reinterpret_cast<const float4*>(gbase + off);
                    } else {
                        buf[p] = make_float4(0.f, 0.f, 0.f, 0.f);
                    }
                }
                #pragma unroll
                for (int p = 0; p < 8; ++p) {
                    acc.x += buf[p].x; acc.y += buf[p].y;
                    acc.z += buf[p].z; acc.w += buf[p].w;
                }
            }

            // Reduce over the 4 sub-groups (lanes differing in bits 4..5).
            acc.x += __shfl_xor(acc.x, 16); acc.y += __shfl_xor(acc.y, 16);
            acc.z += __shfl_xor(acc.z, 16); acc.w += __shfl_xor(acc.w, 16);
            acc.x += __shfl_xor(acc.x, 32); acc.y += __shfl_xor(acc.y, 32);
            acc.z += __shfl_xor(acc.z, 32); acc.w += __shfl_xor(acc.w, 32);

            if (sub == 0) {
                const float inv = 1.0f / (float)cnt;
                float4 r = make_float4(acc.x * inv, acc.y * inv,
                                       acc.z * inv, acc.w * inv);
                *reinterpret_cast<float4*>(out + ((size_t)b * num_segments + s) * FEAT + fq * 4) = r;
            }
        }
    }
}

extern "C" void kernel_launch(void* const* d_in, const int* in_sizes, int n_in,
                              void* d_out, int out_size, void* d_ws, size_t ws_size,
                              hipStream_t stream)
{
    const float* gene         = (const float*)d_in[0];
    const int*   flat_indices = (const int*)d_in[1];
    const int*   segment_ids  = (const int*)d_in[2];
    const int*   counts       = (const int*)d_in[3];
    float*       out          = (float*)d_out;

    const int total        = in_sizes[1];
    const int num_segments = in_sizes[3];

    int* starts  = (int*)d_ws;                     // num_segments ints
    int* workctr = starts + num_segments;          // 8 ints

    find_starts_kernel<<<(total + 255) / 256, 256, 0, stream>>>(segment_ids, starts,
                                                                workctr, total);

    const int nblocks = 2048;                      // 8 blocks/CU, persistent
    genesets_pool_kernel<<<nblocks, 256, 0, stream>>>(gene, flat_indices, starts,
                                                      counts, out, num_segments,
                                                      workctr);
}

// Round 9
// 32.927 us; speedup vs baseline: 8.9900x; 8.9900x over previous
//
#include <hip/hip_runtime.h>

#define BATCH 8
#define NUM_GENES 20000
#define FEAT 64

// Pass 1: find segment start offsets from sorted segment_ids.
__global__ __launch_bounds__(256)
void find_starts_kernel(const int* __restrict__ segment_ids,
                        int* __restrict__ starts, int total)
{
    int i = blockIdx.x * 256 + threadIdx.x;
    if (i < total) {
        int s = segment_ids[i];
        if (i == 0 || segment_ids[i - 1] != s) starts[s] = i;
    }
}

// Pass 2: 128-thread blocks = 2 waves; wave w handles segment pair*2+w,
// batch b = bid & 7 (XCD pinning: verified R2, FETCH 157->70 MB).
// 2-wave blocks -> 16 workgroups/CU -> up to 32 waves/CU (R4's 256-thr
// shape measured only ~58% occupancy; R2's small blocks ~72%).
// lane = sub*16 + fq; sub picks one of 4 gene rows per gather, fq the
// float4 feature quad. Indices staged pre-scaled (idx*FEAT, 32-bit safe),
// broadcast via __shfl. Inner loop: depth-8 issue-then-drain sawtooth
// (verified R5: -25%; depth 12 and double-buffer both no better).
// NO dynamic work queue: R8 showed cross-XCD atomic counters cost ~9x.
__global__ __launch_bounds__(128, 8)
void genesets_pool_kernel(const float* __restrict__ gene,        // [B][G][F]
                          const int*   __restrict__ flat_indices,// [total]
                          const int*   __restrict__ starts,      // [S]
                          const int*   __restrict__ counts,      // [S]
                          float*       __restrict__ out,         // [B][S][F]
                          int num_segments)
{
    const int bid  = blockIdx.x;
    const int b    = bid & 7;                      // batch -> XCD
    const int wave = threadIdx.x >> 6;             // 0..1
    const int s    = (bid >> 3) * 2 + wave;        // segment
    const int lane = threadIdx.x & 63;
    const int sub  = lane >> 4;                    // 0..3
    const int fq   = lane & 15;                    // feature quad

    if (s >= num_segments) return;

    const int start = starts[s];
    const int cnt   = counts[s];

    // Stage all indices, pre-scaled to element offsets (cnt < 128).
    int off_a = (lane      < cnt) ? flat_indices[start + lane]      * FEAT : 0;
    int off_b = (lane + 64 < cnt) ? flat_indices[start + lane + 64] * FEAT : 0;

    const float* gbase = gene + (size_t)b * NUM_GENES * FEAT + fq * 4;

    float4 acc = make_float4(0.f, 0.f, 0.f, 0.f);
    const int kn = (cnt + 3) >> 2;                 // quads, <= 23

    for (int c = 0; c < kn; c += 8) {
        float4 buf[8];
        #pragma unroll
        for (int p = 0; p < 8; ++p) {
            const int j = sub + 4 * (c + p);
            const int off = (j < 64) ? __shfl(off_a, j) : __shfl(off_b, j & 63);
            if (j < cnt) {                         // subsumes k < kn
                buf[p] = *reinterpret_cast<const float4*>(gbase + off);
            } else {
                buf[p] = make_float4(0.f, 0.f, 0.f, 0.f);
            }
        }
        #pragma unroll
        for (int p = 0; p < 8; ++p) {
            acc.x += buf[p].x; acc.y += buf[p].y;
            acc.z += buf[p].z; acc.w += buf[p].w;
        }
    }

    // Reduce over the 4 sub-groups (lanes differing in bits 4..5).
    acc.x += __shfl_xor(acc.x, 16); acc.y += __shfl_xor(acc.y, 16);
    acc.z += __shfl_xor(acc.z, 16); acc.w += __shfl_xor(acc.w, 16);
    acc.x += __shfl_xor(acc.x, 32); acc.y += __shfl_xor(acc.y, 32);
    acc.z += __shfl_xor(acc.z, 32); acc.w += __shfl_xor(acc.w, 32);

    if (sub == 0) {
        const float inv = 1.0f / (float)cnt;
        float4 r = make_float4(acc.x * inv, acc.y * inv, acc.z * inv, acc.w * inv);
        *reinterpret_cast<float4*>(out + ((size_t)b * num_segments + s) * FEAT + fq * 4) = r;
    }
}

extern "C" void kernel_launch(void* const* d_in, const int* in_sizes, int n_in,
                              void* d_out, int out_size, void* d_ws, size_t ws_size,
                              hipStream_t stream)
{
    const float* gene         = (const float*)d_in[0];
    const int*   flat_indices = (const int*)d_in[1];
    const int*   segment_ids  = (const int*)d_in[2];
    const int*   counts       = (const int*)d_in[3];
    float*       out          = (float*)d_out;

    const int total        = in_sizes[1];
    const int num_segments = in_sizes[3];

    int* starts = (int*)d_ws;          // num_segments ints of scratch

    find_starts_kernel<<<(total + 255) / 256, 256, 0, stream>>>(segment_ids, starts, total);

    const int seg_pairs = (num_segments + 1) / 2;
    const int nblocks   = seg_pairs * BATCH;
    genesets_pool_kernel<<<nblocks, 128, 0, stream>>>(gene, flat_indices, starts,
                                                      counts, out, num_segments);
}